// Round 16
// baseline (52.625 us; speedup 1.0000x reference)
//
#include <hip/hip_runtime.h>

// NCuts loss: seg [8,4,224,224], padded_seg [8,4,232,232],
// weight [8,1,224,224,9,9], sum_weight [8,1,224,224] -> out[8] (fp32)
//
// R15 (DPP tap loop) with ONE structural change: weight LDS is SINGLE-
// buffered (18.1 KB) -> block LDS 33.8 KB -> 4 blocks/CU, grid 1024 =
// exactly 4 x 256 CUs: all blocks resident from t=0 (no scheduling tail),
// 32 waves/CU. Intra-block prefetch is replaced by inter-block overlap:
// while one block waits on its weight DMA, the other 3 compute.
// __launch_bounds__(512,8) caps VGPR at 64 for the 4-block residency.
//  - psg window [15][4][64] staged once via global_load_lds; seg read from
//    window interior; sum_weight recomputed from staged weights.
//  - DPP tap loop: wave w owns window-row w (row 8 split over waves 0-3),
//    1 ds_read_b32 per (row,class) + cumulative wave_shl:1 DPP shifts.
//  - single block-end reduction; XCD-swizzled block ids.

constexpr int NN  = 8;
constexpr int KK  = 4;
constexpr int HH  = 224;
constexpr int WW  = 224;
constexpr int PAD = 4;                   // RADIUS-1
constexpr int HP  = HH + 2 * PAD;        // 232
constexpr int WP  = WW + 2 * PAD;        // 232
constexpr int NWIN = 81;
constexpr int PIX = HH * WW;             // 50176
constexpr int TPB = 512;                 // 8 waves
constexpr int PPB = 56;                  // strip width
constexpr int RPB = 7;                   // rows per block
constexpr int CSP = WW / PPB;            // 4 col-strips
constexpr int GPI = HH / RPB;            // 32 row-groups
constexpr int BPI = GPI * CSP;           // 128 blocks per image
constexpr int NBLK = NN * BPI;           // 1024 blocks = 4 * 256 CUs
constexpr int PLANE = HP * WP;           // 53824
constexpr int WCOL = PPB + 8;            // 64 window cols
constexpr int NSLOT = RPB + 8;           // 15 window rows
constexpr int PSG_F4 = NSLOT * KK * (WCOL / 4);  // 960 f4 = 15.4 KB
constexpr int WSLAB = PPB * NWIN;        // 4536 floats per weight tile
constexpr int WF4 = WSLAB / 4;           // 1134 f4

#define GLL16(gptr, lptr)                                            \
    __builtin_amdgcn_global_load_lds(                                \
        (const __attribute__((address_space(1))) void*)(gptr),       \
        (__attribute__((address_space(3))) void*)(lptr), 16, 0, 0)

// lane i <- lane i+1 (zero-fill at lane 63), wave_shl:1 (DppCtrl 0x130)
__device__ __forceinline__ float dpp_shl1(float x) {
    int r = __builtin_amdgcn_update_dpp(
        0, __builtin_bit_cast(int, x), 0x130 /*WAVE_SHL1*/, 0xF, 0xF, true);
    return __builtin_bit_cast(float, r);
}

// full window-row M, all 4 classes, via DPP shifts
template<int M>
__device__ __forceinline__ void do_mrow(const float* __restrict__ lwp,
                                        const float* __restrict__ pbase,
                                        float acc[KK], float& wsum) {
    float wv[9];
#pragma unroll
    for (int j = 0; j < 9; ++j) wv[j] = lwp[9 * M + j];
#pragma unroll
    for (int j = 0; j < 9; ++j) wsum += wv[j];
    float q0 = pbase[(M * KK + 0) * WCOL];
    float q1 = pbase[(M * KK + 1) * WCOL];
    float q2 = pbase[(M * KK + 2) * WCOL];
    float q3 = pbase[(M * KK + 3) * WCOL];
    acc[0] += q0 * wv[0]; acc[1] += q1 * wv[0];
    acc[2] += q2 * wv[0]; acc[3] += q3 * wv[0];
#pragma unroll
    for (int j = 1; j < 9; ++j) {
        q0 = dpp_shl1(q0); q1 = dpp_shl1(q1);
        q2 = dpp_shl1(q2); q3 = dpp_shl1(q3);
        acc[0] += q0 * wv[j]; acc[1] += q1 * wv[j];
        acc[2] += q2 * wv[j]; acc[3] += q3 * wv[j];
    }
}

// single class C of window-row 8 (optionally owns row-8 wsum)
template<int C, bool WSUM8>
__device__ __forceinline__ void do_m8c(const float* __restrict__ lwp,
                                       const float* __restrict__ pbase,
                                       float acc[KK], float& wsum) {
    float wv[9];
#pragma unroll
    for (int j = 0; j < 9; ++j) wv[j] = lwp[72 + j];
    if (WSUM8) {
#pragma unroll
        for (int j = 0; j < 9; ++j) wsum += wv[j];
    }
    float q = pbase[(8 * KK + C) * WCOL];
    acc[C] += q * wv[0];
#pragma unroll
    for (int j = 1; j < 9; ++j) {
        q = dpp_shl1(q);
        acc[C] += q * wv[j];
    }
}

__global__ __launch_bounds__(TPB, 8) void ncuts_stage1(
    const float* __restrict__ seg, const float* __restrict__ pseg,
    const float* __restrict__ wgt, const float* __restrict__ swgt,
    float* __restrict__ part)
{
    const int hw   = blockIdx.x;
    const int b    = (hw & 7) * (NBLK / 8) + (hw >> 3);  // XCD swizzle (bijective)
    const int n    = b / BPI;
    const int r    = b - n * BPI;
    const int rg   = r >> 2;                 // row-group 0..31
    const int cs   = r & 3;                  // col-strip 0..3
    const int h0   = rg * RPB;
    const int w0   = cs * PPB;
    const int tid  = threadIdx.x;
    const int wv_  = tid >> 6;               // 0..7
    const int lane = tid & 63;

    __shared__ float lds_w[WSLAB];                     // 18144 B (single buffer)
    __shared__ float psg_lds[NSLOT * KK * WCOL];       // 15360 B
    __shared__ float lred[8][8];                       // 256 B -> 33760 B

    const size_t nb = (size_t)n * KK * PLANE;

    // ---- weight tile stager ----
    auto stage_w = [&](int s) {
        const float4* wsrc = (const float4*)(
            wgt + ((size_t)n * PIX + (size_t)(h0 + s) * WW + w0) * NWIN);
#pragma unroll
        for (int k = 0; k < 3; ++k) {
            const int i = k * TPB + tid;
            if (i < WF4)
                GLL16(wsrc + i, lds_w + ((k * TPB + (tid & ~63)) << 2));
        }
    };

    stage_w(0);                               // async: weight tile 0

    // ---- psg window prologue: [15 slots][4 cls][64 cols], 960 f4 ----
#pragma unroll
    for (int k = 0; k < 2; ++k) {
        const int i = k * TPB + tid;
        if (i < PSG_F4) {
            const int slot = i >> 6;              // 64 f4 per slot
            const int c    = (i >> 4) & 3;
            const int c4   = i & 15;
            const float* src = pseg + nb + (size_t)c * PLANE +
                               (size_t)(h0 + slot) * WP + w0 + c4 * 4;
            GLL16(src, psg_lds + ((k * TPB + (tid & ~63)) << 2));
        }
    }

    float rA[KK] = {0.f, 0.f, 0.f, 0.f};
    float rV[KK] = {0.f, 0.f, 0.f, 0.f};

    __syncthreads();   // psg window + weight tile 0 landed

    const int wlane = (lane < PPB) ? lane : (PPB - 1);   // clamp for w-reads

    #pragma unroll 1
    for (int s = 0; s < RPB; ++s) {
        // ---- compute row s: ALL 64 lanes (DPP needs full exec) ----
        {
            const float* lwp   = lds_w + wlane * NWIN;
            const float* pbase = psg_lds + (size_t)s * KK * WCOL + lane;
            float acc[KK] = {0.f, 0.f, 0.f, 0.f};
            float wsum = 0.f;
            switch (wv_) {
                case 0: do_mrow<0>(lwp, pbase, acc, wsum);
                        do_m8c<0, true>(lwp, pbase, acc, wsum);  break;
                case 1: do_mrow<1>(lwp, pbase, acc, wsum);
                        do_m8c<1, false>(lwp, pbase, acc, wsum); break;
                case 2: do_mrow<2>(lwp, pbase, acc, wsum);
                        do_m8c<2, false>(lwp, pbase, acc, wsum); break;
                case 3: do_mrow<3>(lwp, pbase, acc, wsum);
                        do_m8c<3, false>(lwp, pbase, acc, wsum); break;
                case 4: do_mrow<4>(lwp, pbase, acc, wsum); break;
                case 5: do_mrow<5>(lwp, pbase, acc, wsum); break;
                case 6: do_mrow<6>(lwp, pbase, acc, wsum); break;
                default: do_mrow<7>(lwp, pbase, acc, wsum); break;
            }
            if (lane < PPB) {
                float segv[KK];
#pragma unroll
                for (int c = 0; c < KK; ++c)      // seg = window interior
                    segv[c] = pbase[((4 * KK) + c) * WCOL + 4];
#pragma unroll
                for (int c = 0; c < KK; ++c) {
                    rA[c] += acc[c] * segv[c];
                    rV[c] += wsum   * segv[c];
                }
            }
        }
        __syncthreads();                      // buffer consumed by all waves
        if (s + 1 < RPB) {
            stage_w(s + 1);                   // serial stage (inter-block TLP
            __syncthreads();                  //   covers the DMA wait)
        }
    }

    // ---- single block-end reduction ----
    float vals[8] = { rA[0], rA[1], rA[2], rA[3], rV[0], rV[1], rV[2], rV[3] };
#pragma unroll
    for (int i = 0; i < 8; ++i) {
        float v = vals[i];
#pragma unroll
        for (int off = 32; off > 0; off >>= 1) v += __shfl_down(v, off, 64);
        if (lane == 0) lred[wv_][i] = v;
    }
    __syncthreads();
    if (tid < 8) {
        float ssum = 0.f;
#pragma unroll
        for (int w = 0; w < 8; ++w) ssum += lred[w][tid];
        part[(size_t)b * 8 + tid] = ssum;
    }
}

__global__ __launch_bounds__(256) void ncuts_stage2(
    const float* __restrict__ part, float* __restrict__ out)
{
    const int n   = blockIdx.x;
    const int tid = threadIdx.x;

    float vals[8] = {0.f, 0.f, 0.f, 0.f, 0.f, 0.f, 0.f, 0.f};
    for (int bb = tid; bb < BPI; bb += 256) {       // 128 entries per image
        const float* q = part + ((size_t)(n * BPI + bb)) * 8;
#pragma unroll
        for (int i = 0; i < 8; ++i) vals[i] += q[i];
    }

    __shared__ float lred[4][8];
    const int lane = tid & 63;
    const int wv_  = tid >> 6;
#pragma unroll
    for (int i = 0; i < 8; ++i) {
        float v = vals[i];
#pragma unroll
        for (int off = 32; off > 0; off >>= 1) v += __shfl_down(v, off, 64);
        if (lane == 0) lred[wv_][i] = v;
    }
    __syncthreads();
    if (tid == 0) {
        float assoc = 0.f;
#pragma unroll
        for (int k = 0; k < 4; ++k) {
            const float A = lred[0][k] + lred[1][k] + lred[2][k] + lred[3][k];
            const float V = lred[0][4 + k] + lred[1][4 + k] + lred[2][4 + k] + lred[3][4 + k];
            assoc += A / V;
        }
        out[n] = 4.0f - assoc;
    }
}

extern "C" void kernel_launch(void* const* d_in, const int* in_sizes, int n_in,
                              void* d_out, int out_size, void* d_ws, size_t ws_size,
                              hipStream_t stream) {
    const float* seg  = (const float*)d_in[0];
    const float* pseg = (const float*)d_in[1];
    const float* wgt  = (const float*)d_in[2];
    const float* swgt = (const float*)d_in[3];
    float* out  = (float*)d_out;
    float* part = (float*)d_ws;   // 1024 blocks * 8 floats = 32768 B

    ncuts_stage1<<<NBLK, TPB, 0, stream>>>(seg, pseg, wgt, swgt, part);
    ncuts_stage2<<<NN, 256, 0, stream>>>(part, out);
}

// Round 17
// 32.343 us; speedup vs baseline: 1.6271x; 1.6271x over previous
//
#include <hip/hip_runtime.h>

// NCuts loss: seg [8,4,224,224], padded_seg [8,4,232,232],
// weight [8,1,224,224,9,9], sum_weight [8,1,224,224] -> out[8] (fp32)
//
// R15 compute core verbatim (DPP tap loop, weight dbuf global_load_lds
// prefetch, psg window via global_load_lds, seg-from-window, wsum
// recompute, single block-end reduction, XCD swizzle) with ONE change:
// RPB 7 -> 14. Grid = 8 img x 16 rowgrp x 4 strips = 512 blocks = EXACTLY
// 2 blocks/CU (LDS 59.1 KB): all blocks resident from t=0, zero scheduling
// tail (R15's 1024 @ 3/CU = 1.33 rounds -> ~25% tail). psg halo traffic
// drops (22 window rows / 14 output rows vs 15/7).
// launch_bounds(512,4) -> VGPR cap 128 (R16's (512,8) forced VGPR=32 and
// 78 MB of scratch spill -- never cap below ~85).

constexpr int NN  = 8;
constexpr int KK  = 4;
constexpr int HH  = 224;
constexpr int WW  = 224;
constexpr int PAD = 4;                   // RADIUS-1
constexpr int HP  = HH + 2 * PAD;        // 232
constexpr int WP  = WW + 2 * PAD;        // 232
constexpr int NWIN = 81;
constexpr int PIX = HH * WW;             // 50176
constexpr int TPB = 512;                 // 8 waves
constexpr int PPB = 56;                  // strip width
constexpr int RPB = 14;                  // rows per block
constexpr int CSP = WW / PPB;            // 4 col-strips
constexpr int GPI = HH / RPB;            // 16 row-groups
constexpr int BPI = GPI * CSP;           // 64 blocks per image
constexpr int NBLK = NN * BPI;           // 512 blocks = 2 * 256 CUs
constexpr int PLANE = HP * WP;           // 53824
constexpr int WCOL = PPB + 8;            // 64 window cols
constexpr int NSLOT = RPB + 8;           // 22 window rows
constexpr int PSG_F4 = NSLOT * KK * (WCOL / 4);  // 1408 f4 = 22.5 KB
constexpr int WSLAB = PPB * NWIN;        // 4536 floats per weight tile
constexpr int WF4 = WSLAB / 4;           // 1134 f4

#define GLL16(gptr, lptr)                                            \
    __builtin_amdgcn_global_load_lds(                                \
        (const __attribute__((address_space(1))) void*)(gptr),       \
        (__attribute__((address_space(3))) void*)(lptr), 16, 0, 0)

// lane i <- lane i+1 (zero-fill at lane 63), wave_shl:1 (DppCtrl 0x130)
__device__ __forceinline__ float dpp_shl1(float x) {
    int r = __builtin_amdgcn_update_dpp(
        0, __builtin_bit_cast(int, x), 0x130 /*WAVE_SHL1*/, 0xF, 0xF, true);
    return __builtin_bit_cast(float, r);
}

// full window-row M, all 4 classes, via DPP shifts
template<int M>
__device__ __forceinline__ void do_mrow(const float* __restrict__ lwp,
                                        const float* __restrict__ pbase,
                                        float acc[KK], float& wsum) {
    float wv[9];
#pragma unroll
    for (int j = 0; j < 9; ++j) wv[j] = lwp[9 * M + j];
#pragma unroll
    for (int j = 0; j < 9; ++j) wsum += wv[j];
    float q0 = pbase[(M * KK + 0) * WCOL];
    float q1 = pbase[(M * KK + 1) * WCOL];
    float q2 = pbase[(M * KK + 2) * WCOL];
    float q3 = pbase[(M * KK + 3) * WCOL];
    acc[0] += q0 * wv[0]; acc[1] += q1 * wv[0];
    acc[2] += q2 * wv[0]; acc[3] += q3 * wv[0];
#pragma unroll
    for (int j = 1; j < 9; ++j) {
        q0 = dpp_shl1(q0); q1 = dpp_shl1(q1);
        q2 = dpp_shl1(q2); q3 = dpp_shl1(q3);
        acc[0] += q0 * wv[j]; acc[1] += q1 * wv[j];
        acc[2] += q2 * wv[j]; acc[3] += q3 * wv[j];
    }
}

// single class C of window-row 8 (optionally owns row-8 wsum)
template<int C, bool WSUM8>
__device__ __forceinline__ void do_m8c(const float* __restrict__ lwp,
                                       const float* __restrict__ pbase,
                                       float acc[KK], float& wsum) {
    float wv[9];
#pragma unroll
    for (int j = 0; j < 9; ++j) wv[j] = lwp[72 + j];
    if (WSUM8) {
#pragma unroll
        for (int j = 0; j < 9; ++j) wsum += wv[j];
    }
    float q = pbase[(8 * KK + C) * WCOL];
    acc[C] += q * wv[0];
#pragma unroll
    for (int j = 1; j < 9; ++j) {
        q = dpp_shl1(q);
        acc[C] += q * wv[j];
    }
}

__global__ __launch_bounds__(TPB, 4) void ncuts_stage1(
    const float* __restrict__ seg, const float* __restrict__ pseg,
    const float* __restrict__ wgt, const float* __restrict__ swgt,
    float* __restrict__ part)
{
    const int hw   = blockIdx.x;
    const int b    = (hw & 7) * (NBLK / 8) + (hw >> 3);  // XCD swizzle (bijective)
    const int n    = b / BPI;
    const int r    = b - n * BPI;
    const int rg   = r >> 2;                 // row-group 0..15
    const int cs   = r & 3;                  // col-strip 0..3
    const int h0   = rg * RPB;
    const int w0   = cs * PPB;
    const int tid  = threadIdx.x;
    const int wv_  = tid >> 6;               // 0..7
    const int lane = tid & 63;

    __shared__ float lds_w[2 * WSLAB];                 // 36288 B (dbuf)
    __shared__ float psg_lds[NSLOT * KK * WCOL];       // 22528 B
    __shared__ float lred[8][8];                       // 256 B -> 59072 B

    const size_t nb = (size_t)n * KK * PLANE;

    // ---- weight tile stager (R13/R15-proven) ----
    auto stage_w = [&](int buf, int s) {
        const float4* wsrc = (const float4*)(
            wgt + ((size_t)n * PIX + (size_t)(h0 + s) * WW + w0) * NWIN);
        float* base = lds_w + buf * WSLAB;
#pragma unroll
        for (int k = 0; k < 3; ++k) {
            const int i = k * TPB + tid;
            if (i < WF4)
                GLL16(wsrc + i, base + ((k * TPB + (tid & ~63)) << 2));
        }
    };

    stage_w(0, 0);                            // async: weight tile 0

    // ---- psg window prologue: [22 slots][4 cls][64 cols], 1408 f4 ----
#pragma unroll
    for (int k = 0; k < 3; ++k) {
        const int i = k * TPB + tid;
        if (i < PSG_F4) {
            const int slot = i >> 6;              // 64 f4 per slot
            const int c    = (i >> 4) & 3;
            const int c4   = i & 15;
            const float* src = pseg + nb + (size_t)c * PLANE +
                               (size_t)(h0 + slot) * WP + w0 + c4 * 4;
            GLL16(src, psg_lds + ((k * TPB + (tid & ~63)) << 2));
        }
    }

    float rA[KK] = {0.f, 0.f, 0.f, 0.f};
    float rV[KK] = {0.f, 0.f, 0.f, 0.f};

    __syncthreads();   // psg window + weight tile 0 landed

    const int wlane = (lane < PPB) ? lane : (PPB - 1);   // clamp for w-reads

    int cur = 0;
#pragma unroll 1
    for (int s = 0; s < RPB; ++s) {
        // ---- prefetch next row-tile's weights into the other buffer ----
        if (s + 1 < RPB) stage_w(cur ^ 1, s + 1);

        // ---- compute row s: ALL 64 lanes (DPP needs full exec) ----
        {
            const float* lwp   = lds_w + cur * WSLAB + wlane * NWIN;
            const float* pbase = psg_lds + (size_t)s * KK * WCOL + lane;
            float acc[KK] = {0.f, 0.f, 0.f, 0.f};
            float wsum = 0.f;
            switch (wv_) {
                case 0: do_mrow<0>(lwp, pbase, acc, wsum);
                        do_m8c<0, true>(lwp, pbase, acc, wsum);  break;
                case 1: do_mrow<1>(lwp, pbase, acc, wsum);
                        do_m8c<1, false>(lwp, pbase, acc, wsum); break;
                case 2: do_mrow<2>(lwp, pbase, acc, wsum);
                        do_m8c<2, false>(lwp, pbase, acc, wsum); break;
                case 3: do_mrow<3>(lwp, pbase, acc, wsum);
                        do_m8c<3, false>(lwp, pbase, acc, wsum); break;
                case 4: do_mrow<4>(lwp, pbase, acc, wsum); break;
                case 5: do_mrow<5>(lwp, pbase, acc, wsum); break;
                case 6: do_mrow<6>(lwp, pbase, acc, wsum); break;
                default: do_mrow<7>(lwp, pbase, acc, wsum); break;
            }
            if (lane < PPB) {
                float segv[KK];
#pragma unroll
                for (int c = 0; c < KK; ++c)      // seg = window interior
                    segv[c] = pbase[((4 * KK) + c) * WCOL + 4];
#pragma unroll
                for (int c = 0; c < KK; ++c) {
                    rA[c] += acc[c] * segv[c];
                    rV[c] += wsum   * segv[c];
                }
            }
        }
        __syncthreads();   // tile consumed; prefetch drained (overlap across
        cur ^= 1;          //   the 2 resident blocks + 8 waves on this CU)
    }

    // ---- single block-end reduction ----
    float vals[8] = { rA[0], rA[1], rA[2], rA[3], rV[0], rV[1], rV[2], rV[3] };
#pragma unroll
    for (int i = 0; i < 8; ++i) {
        float v = vals[i];
#pragma unroll
        for (int off = 32; off > 0; off >>= 1) v += __shfl_down(v, off, 64);
        if (lane == 0) lred[wv_][i] = v;
    }
    __syncthreads();
    if (tid < 8) {
        float ssum = 0.f;
#pragma unroll
        for (int w = 0; w < 8; ++w) ssum += lred[w][tid];
        part[(size_t)b * 8 + tid] = ssum;
    }
}

__global__ __launch_bounds__(256) void ncuts_stage2(
    const float* __restrict__ part, float* __restrict__ out)
{
    const int n   = blockIdx.x;
    const int tid = threadIdx.x;

    float vals[8] = {0.f, 0.f, 0.f, 0.f, 0.f, 0.f, 0.f, 0.f};
    for (int bb = tid; bb < BPI; bb += 256) {       // 64 entries per image
        const float* q = part + ((size_t)(n * BPI + bb)) * 8;
#pragma unroll
        for (int i = 0; i < 8; ++i) vals[i] += q[i];
    }

    __shared__ float lred[4][8];
    const int lane = tid & 63;
    const int wv_  = tid >> 6;
#pragma unroll
    for (int i = 0; i < 8; ++i) {
        float v = vals[i];
#pragma unroll
        for (int off = 32; off > 0; off >>= 1) v += __shfl_down(v, off, 64);
        if (lane == 0) lred[wv_][i] = v;
    }
    __syncthreads();
    if (tid == 0) {
        float assoc = 0.f;
#pragma unroll
        for (int k = 0; k < 4; ++k) {
            const float A = lred[0][k] + lred[1][k] + lred[2][k] + lred[3][k];
            const float V = lred[0][4 + k] + lred[1][4 + k] + lred[2][4 + k] + lred[3][4 + k];
            assoc += A / V;
        }
        out[n] = 4.0f - assoc;
    }
}

extern "C" void kernel_launch(void* const* d_in, const int* in_sizes, int n_in,
                              void* d_out, int out_size, void* d_ws, size_t ws_size,
                              hipStream_t stream) {
    const float* seg  = (const float*)d_in[0];
    const float* pseg = (const float*)d_in[1];
    const float* wgt  = (const float*)d_in[2];
    const float* swgt = (const float*)d_in[3];
    float* out  = (float*)d_out;
    float* part = (float*)d_ws;   // 512 blocks * 8 floats = 16384 B

    ncuts_stage1<<<NBLK, TPB, 0, stream>>>(seg, pseg, wgt, swgt, part);
    ncuts_stage2<<<NN, 256, 0, stream>>>(part, out);
}